// Round 14
// baseline (229.907 us; speedup 1.0000x reference)
//
#include <hip/hip_runtime.h>

#define NUM_DEM 2
#define VOCAB 10000
#define EMB 128
#define NROWS 16384
#define ROWLEN (NUM_DEM + VOCAB)      // 10002
#define KSTEPS 313                    // ceil(10000/32)
#define PCOLS 129                     // partial row stride: 128 pooled + 1 count
#define BPACK_USHORTS ((size_t)KSTEPS * 4096)
#define BPACK_BYTES (BPACK_USHORTS * 2)
#define NCH 8

typedef float f32x4 __attribute__((ext_vector_type(4)));
typedef __bf16 bf16x8 __attribute__((ext_vector_type(8)));
typedef short s16x8 __attribute__((ext_vector_type(8)));

union Frag {
    s16x8 s;
    bf16x8 b;
    unsigned int u[4];
};

__device__ __forceinline__ unsigned short f2bf_rtne(float f) {
    unsigned int u = __float_as_uint(f);
    u += 0x7FFFu + ((u >> 16) & 1u);
    return (unsigned short)(u >> 16);
}

// ---------------- kernel 0: pack embed (fp32 -> bf16 MFMA-B fragment order) ---------
// Bpack[((t*8 + c)*64 + l)*8 + j] = bf16(embed[t*32 + (l>>4)*8 + j][c*16 + (l&15)])
__global__ void pack_embed_k(const float* __restrict__ embed,
                             unsigned short* __restrict__ bp) {
    int id = blockIdx.x * blockDim.x + threadIdx.x;
    if (id >= KSTEPS * 8 * 64) return;
    int l = id & 63;
    int c = (id >> 6) & 7;
    int t = id >> 9;
    int kbase = t * 32 + ((l >> 4) * 8);
    int n = c * 16 + (l & 15);
    unsigned short v[8];
#pragma unroll
    for (int j = 0; j < 8; ++j) {
        int k = kbase + j;
        float f = (k < VOCAB) ? embed[(size_t)k * EMB + n] : 0.0f;
        v[j] = f2bf_rtne(f);
    }
    uint4 w;
    w.x = (unsigned int)v[0] | ((unsigned int)v[1] << 16);
    w.y = (unsigned int)v[2] | ((unsigned int)v[3] << 16);
    w.z = (unsigned int)v[4] | ((unsigned int)v[5] << 16);
    w.w = (unsigned int)v[6] | ((unsigned int)v[7] << 16);
    *reinterpret_cast<uint4*>(bp + (size_t)id * 8) = w;
}

// ---------------- kernel 1: split-K masked-sum GEMM via MFMA ------------------------
// R13 structure scaled to M=256 rows per block (1024 threads, 16 waves): B-restaging
// halves again (327 -> 164 MB). Per thread: 1 global_load_lds/iter (wave-half picks
// the K-step) + same A pattern. nch=8 keeps grid at 512 blocks.
typedef const __attribute__((address_space(1))) unsigned int* gas_u32p;
typedef __attribute__((address_space(3))) unsigned int* las_u32p;
#define GLOAD_LDS16(g, l)                                                              \
    __builtin_amdgcn_global_load_lds((gas_u32p)(g), (las_u32p)(l), 16, 0, 0)

#define PERM_A(dst, x0, x1)                                                            \
    dst.u[0] = __builtin_amdgcn_perm(__float_as_uint(x0.y), __float_as_uint(x0.x),     \
                                     0x07060302u);                                     \
    dst.u[1] = __builtin_amdgcn_perm(__float_as_uint(x0.w), __float_as_uint(x0.z),     \
                                     0x07060302u);                                     \
    dst.u[2] = __builtin_amdgcn_perm(__float_as_uint(x1.y), __float_as_uint(x1.x),     \
                                     0x07060302u);                                     \
    dst.u[3] = __builtin_amdgcn_perm(__float_as_uint(x1.w), __float_as_uint(x1.z),     \
                                     0x07060302u);

__global__ __launch_bounds__(1024, 1) void main_gemm_k(
    const float* __restrict__ src, const unsigned short* __restrict__ bp,
    float* __restrict__ part, int nch) {
    __shared__ alignas(16) unsigned short ldsB[2 * 4096];  // 16 KB: two K-step B tiles

    const int tid = threadIdx.x;
    const int lane = tid & 63;
    const int wid = tid >> 6;        // 0..15
    const int half = wid >> 3;       // 0: stage step t, 1: stage step t+1
    const int sidx = tid & 511;      // staging slot within the half's 8 KB tile
    const int rb = blockIdx.x & 63;  // row block: 256 rows
    const int ch = blockIdx.x >> 6;  // K chunk
    const int t0 = (KSTEPS * ch) / nch;
    const int t1 = (KSTEPS * (ch + 1)) / nch;

    const int rowbase = rb * 256 + wid * 16;
    const int arow = rowbase + (lane & 15);
    const int kgrp8 = (lane >> 4) * 8;
    const float* asrc = src + (size_t)arow * ROWLEN + NUM_DEM + kgrp8;

    f32x4 pacc[8];
#pragma unroll
    for (int f = 0; f < 8; ++f) pacc[f] = (f32x4){0.f, 0.f, 0.f, 0.f};
    f32x4 cacc = (f32x4){0.f, 0.f, 0.f, 0.f};

    Frag onesf;  // B fragment with col 0 == 1.0 (for row counts), others 0
    {
        unsigned short o = ((lane & 15) == 0) ? (unsigned short)0x3F80 : (unsigned short)0;
        unsigned int ow = (unsigned int)o | ((unsigned int)o << 16);
        onesf.u[0] = ow; onesf.u[1] = ow; onesf.u[2] = ow; onesf.u[3] = ow;
    }

    int t = t0;
    for (; t + 2 <= t1; t += 2) {
        // stage B(t) -> buf0 (waves 0-7), B(t+1) -> buf1 (waves 8-15): 16 B/thread
        {
            const unsigned short* gB = bp + (size_t)(t + half) * 4096 + sidx * 8;
            unsigned short* lB = ldsB + half * 4096 + sidx * 8;
            GLOAD_LDS16(gB, lB);
        }

        // A(t), A(t+1): plain caching loads; perm to bf16 immediately (regs die early)
        Frag af0, af1;
        {
            f32x4 z = (f32x4){0.f, 0.f, 0.f, 0.f};
            f32x4 a00 = z, a01 = z, a10 = z, a11 = z;
            if (t * 32 + kgrp8 + 8 <= VOCAB) {
                const f32x4* ap = reinterpret_cast<const f32x4*>(asrc + (size_t)t * 32);
                a00 = ap[0];
                a01 = ap[1];
            }
            if ((t + 1) * 32 + kgrp8 + 8 <= VOCAB) {
                const f32x4* ap =
                    reinterpret_cast<const f32x4*>(asrc + (size_t)(t + 1) * 32);
                a10 = ap[0];
                a11 = ap[1];
            }
            PERM_A(af0, a00, a01);  // truncation fp32->bf16 exact for 0.0/1.0
            PERM_A(af1, a10, a11);
        }

        __syncthreads();  // both B tiles resident

#pragma unroll
        for (int f = 0; f < 8; ++f) {
            Frag bfr;
            bfr.s = *reinterpret_cast<const s16x8*>(ldsB + f * 512 + lane * 8);
            pacc[f] = __builtin_amdgcn_mfma_f32_16x16x32_bf16(af0.b, bfr.b, pacc[f], 0, 0, 0);
        }
        cacc = __builtin_amdgcn_mfma_f32_16x16x32_bf16(af0.b, onesf.b, cacc, 0, 0, 0);
#pragma unroll
        for (int f = 0; f < 8; ++f) {
            Frag bfr;
            bfr.s = *reinterpret_cast<const s16x8*>(ldsB + 4096 + f * 512 + lane * 8);
            pacc[f] = __builtin_amdgcn_mfma_f32_16x16x32_bf16(af1.b, bfr.b, pacc[f], 0, 0, 0);
        }
        cacc = __builtin_amdgcn_mfma_f32_16x16x32_bf16(af1.b, onesf.b, cacc, 0, 0, 0);

        __syncthreads();  // protect LDS before next stage
    }
    if (t < t1) {  // odd tail step
        if (half == 0) {  // wave-uniform branch: waves 0-7 stage the single tile
            const unsigned short* gB = bp + (size_t)t * 4096 + sidx * 8;
            GLOAD_LDS16(gB, ldsB + sidx * 8);
        }
        Frag af0;
        {
            f32x4 z = (f32x4){0.f, 0.f, 0.f, 0.f};
            f32x4 a00 = z, a01 = z;
            if (t * 32 + kgrp8 + 8 <= VOCAB) {
                const f32x4* ap = reinterpret_cast<const f32x4*>(asrc + (size_t)t * 32);
                a00 = ap[0];
                a01 = ap[1];
            }
            PERM_A(af0, a00, a01);
        }
        __syncthreads();
#pragma unroll
        for (int f = 0; f < 8; ++f) {
            Frag bfr;
            bfr.s = *reinterpret_cast<const s16x8*>(ldsB + f * 512 + lane * 8);
            pacc[f] = __builtin_amdgcn_mfma_f32_16x16x32_bf16(af0.b, bfr.b, pacc[f], 0, 0, 0);
        }
        cacc = __builtin_amdgcn_mfma_f32_16x16x32_bf16(af0.b, onesf.b, cacc, 0, 0, 0);
        __syncthreads();
    }

    // epilogue: C/D layout col = lane&15, row = (lane>>4)*4 + reg
    const int rlo = (lane >> 4) * 4;
    float* pch = part + (size_t)ch * NROWS * PCOLS;
#pragma unroll
    for (int f = 0; f < 8; ++f) {
#pragma unroll
        for (int r = 0; r < 4; ++r) {
            int row = rowbase + rlo + r;
            pch[(size_t)row * PCOLS + f * 16 + (lane & 15)] = pacc[f][r];
        }
    }
    if ((lane & 15) == 0) {
#pragma unroll
        for (int r = 0; r < 4; ++r) {
            int row = rowbase + rlo + r;
            pch[(size_t)row * PCOLS + 128] = cacc[r];
        }
    }
}

// ---------------- kernel 2: reduce partials + MLP ----------------------------------
__global__ __launch_bounds__(256) void mlp_k(const float* __restrict__ part,
                                             const float* __restrict__ src,
                                             const float* __restrict__ W1,
                                             const float* __restrict__ b1,
                                             const float* __restrict__ W2,
                                             const float* __restrict__ b2,
                                             float* __restrict__ out, int nch) {
    __shared__ float xls[16][131];  // [dem(2), pooled(128)] per row
    __shared__ float hls[16][16];
    __shared__ float cnt[16];
    const int tid = threadIdx.x;
    const int rb = blockIdx.x * 16;

    if (tid < 16) {
        float s = 0.f;
        for (int c = 0; c < nch; ++c)
            s += part[((size_t)c * NROWS + rb + tid) * PCOLS + 128];
        cnt[tid] = s;
    }
    if (tid >= 16 && tid < 48) {
        int r = (tid - 16) >> 1, d = (tid - 16) & 1;
        xls[r][d] = src[(size_t)(rb + r) * ROWLEN + d];
    }
    __syncthreads();

    for (int idx = tid; idx < 16 * 128; idx += 256) {
        int r = idx >> 7, col = idx & 127;
        float s = 0.f;
        for (int c = 0; c < nch; ++c)
            s += part[((size_t)c * NROWS + rb + r) * PCOLS + col];
        xls[r][NUM_DEM + col] = s / cnt[r];
    }
    __syncthreads();

    {
        int r = tid >> 4, u = tid & 15;
        float acc = b1[u];
        for (int i = 0; i < NUM_DEM + EMB; ++i) acc += xls[r][i] * W1[i * 16 + u];
        hls[r][u] = tanhf(acc);
    }
    __syncthreads();

    if (tid < 32) {
        int r = tid >> 1, o = tid & 1;
        float acc = b2[o];
#pragma unroll
        for (int u = 0; u < 16; ++u) acc += hls[r][u] * W2[u * 2 + o];
        out[(size_t)(rb + r) * 2 + o] = acc;
    }
}

// ---------------- launch ------------------------------------------------------------
extern "C" void kernel_launch(void* const* d_in, const int* in_sizes, int n_in,
                              void* d_out, int out_size, void* d_ws, size_t ws_size,
                              hipStream_t stream) {
    const float* src = (const float*)d_in[0];
    const float* embed = (const float*)d_in[1];
    const float* W1 = (const float*)d_in[2];
    const float* b1 = (const float*)d_in[3];
    const float* W2 = (const float*)d_in[4];
    const float* b2 = (const float*)d_in[5];
    float* out = (float*)d_out;

    unsigned short* bpack = (unsigned short*)d_ws;
    float* part = (float*)((char*)d_ws + BPACK_BYTES);

    const size_t part1 = (size_t)NROWS * PCOLS * sizeof(float);
    int nch = NCH;
    while (nch > 1 && BPACK_BYTES + part1 * (size_t)nch > ws_size) nch >>= 1;

    hipLaunchKernelGGL(pack_embed_k, dim3((KSTEPS * 8 * 64 + 255) / 256), dim3(256), 0,
                       stream, embed, bpack);
    hipLaunchKernelGGL(main_gemm_k, dim3(64 * nch), dim3(1024), 0, stream, src, bpack,
                       part, nch);
    hipLaunchKernelGGL(mlp_k, dim3(NROWS / 16), dim3(256), 0, stream, part, src, W1, b1,
                       W2, b2, out, nch);
}

// Round 15
// 208.592 us; speedup vs baseline: 1.1022x; 1.1022x over previous
//
#include <hip/hip_runtime.h>

#define NUM_DEM 2
#define VOCAB 10000
#define EMB 128
#define NROWS 16384
#define ROWLEN (NUM_DEM + VOCAB)      // 10002
#define KSTEPS 313                    // ceil(10000/32)
#define PCOLS 129                     // partial row stride: 128 pooled + 1 count
#define BPACK_USHORTS ((size_t)KSTEPS * 4096)
#define BPACK_BYTES (BPACK_USHORTS * 2)
#define NCH 8

typedef float f32x4 __attribute__((ext_vector_type(4)));
typedef __bf16 bf16x8 __attribute__((ext_vector_type(8)));
typedef short s16x8 __attribute__((ext_vector_type(8)));

union Frag {
    s16x8 s;
    bf16x8 b;
    unsigned int u[4];
};

__device__ __forceinline__ unsigned short f2bf_rtne(float f) {
    unsigned int u = __float_as_uint(f);
    u += 0x7FFFu + ((u >> 16) & 1u);
    return (unsigned short)(u >> 16);
}

// ---------------- kernel 0: pack embed (fp32 -> bf16 MFMA-B fragment order) ---------
// Bpack[((t*8 + c)*64 + l)*8 + j] = bf16(embed[t*32 + (l>>4)*8 + j][c*16 + (l&15)])
__global__ void pack_embed_k(const float* __restrict__ embed,
                             unsigned short* __restrict__ bp) {
    int id = blockIdx.x * blockDim.x + threadIdx.x;
    if (id >= KSTEPS * 8 * 64) return;
    int l = id & 63;
    int c = (id >> 6) & 7;
    int t = id >> 9;
    int kbase = t * 32 + ((l >> 4) * 8);
    int n = c * 16 + (l & 15);
    unsigned short v[8];
#pragma unroll
    for (int j = 0; j < 8; ++j) {
        int k = kbase + j;
        float f = (k < VOCAB) ? embed[(size_t)k * EMB + n] : 0.0f;
        v[j] = f2bf_rtne(f);
    }
    uint4 w;
    w.x = (unsigned int)v[0] | ((unsigned int)v[1] << 16);
    w.y = (unsigned int)v[2] | ((unsigned int)v[3] << 16);
    w.z = (unsigned int)v[4] | ((unsigned int)v[5] << 16);
    w.w = (unsigned int)v[6] | ((unsigned int)v[7] << 16);
    *reinterpret_cast<uint4*>(bp + (size_t)id * 8) = w;
}

// ---------------- kernel 1: split-K masked-sum GEMM via MFMA ------------------------
// R13 shell (512 threads, 8 waves, BK=64, 16 KB LDS, 2-barrier loop, 2 blocks/CU)
// but each wave owns TWO 16-row tiles (rows +0 and +128): M=256 per block. Each B
// fragment is read from LDS once, used by two MFMAs -> B-restage AND LDS-read
// traffic halve vs R13. nch=8 keeps grid at 512 = 2 blocks/CU.
typedef const __attribute__((address_space(1))) unsigned int* gas_u32p;
typedef __attribute__((address_space(3))) unsigned int* las_u32p;
#define GLOAD_LDS16(g, l)                                                              \
    __builtin_amdgcn_global_load_lds((gas_u32p)(g), (las_u32p)(l), 16, 0, 0)

#define PERM_A(dst, x0, x1)                                                            \
    dst.u[0] = __builtin_amdgcn_perm(__float_as_uint(x0.y), __float_as_uint(x0.x),     \
                                     0x07060302u);                                     \
    dst.u[1] = __builtin_amdgcn_perm(__float_as_uint(x0.w), __float_as_uint(x0.z),     \
                                     0x07060302u);                                     \
    dst.u[2] = __builtin_amdgcn_perm(__float_as_uint(x1.y), __float_as_uint(x1.x),     \
                                     0x07060302u);                                     \
    dst.u[3] = __builtin_amdgcn_perm(__float_as_uint(x1.w), __float_as_uint(x1.z),     \
                                     0x07060302u);

// load A (2 steps) for one row-tile from pointer AP into frags D0 (step t), D1 (t+1)
#define LOAD_A_PAIR(AP, T, D0, D1)                                                     \
    {                                                                                  \
        f32x4 z = (f32x4){0.f, 0.f, 0.f, 0.f};                                         \
        f32x4 a00 = z, a01 = z, a10 = z, a11 = z;                                      \
        if ((T)*32 + kgrp8 + 8 <= VOCAB) {                                             \
            const f32x4* ap = reinterpret_cast<const f32x4*>((AP) + (size_t)(T)*32);   \
            a00 = ap[0];                                                               \
            a01 = ap[1];                                                               \
        }                                                                              \
        if (((T) + 1) * 32 + kgrp8 + 8 <= VOCAB) {                                     \
            const f32x4* ap =                                                          \
                reinterpret_cast<const f32x4*>((AP) + (size_t)((T) + 1) * 32);         \
            a10 = ap[0];                                                               \
            a11 = ap[1];                                                               \
        }                                                                              \
        PERM_A(D0, a00, a01);                                                          \
        PERM_A(D1, a10, a11);                                                          \
    }

__global__ __launch_bounds__(512, 4) void main_gemm_k(
    const float* __restrict__ src, const unsigned short* __restrict__ bp,
    float* __restrict__ part, int nch) {
    __shared__ alignas(16) unsigned short ldsB[2 * 4096];  // 16 KB: two K-step B tiles

    const int tid = threadIdx.x;
    const int lane = tid & 63;
    const int wid = tid >> 6;        // 0..7
    const int rb = blockIdx.x & 63;  // row block: 256 rows
    const int ch = blockIdx.x >> 6;  // K chunk
    const int t0 = (KSTEPS * ch) / nch;
    const int t1 = (KSTEPS * (ch + 1)) / nch;

    const int rowbase0 = rb * 256 + wid * 16;  // tile 0
    const int rowbase1 = rowbase0 + 128;       // tile 1
    const int kgrp8 = (lane >> 4) * 8;
    const float* asrc0 = src + (size_t)(rowbase0 + (lane & 15)) * ROWLEN + NUM_DEM + kgrp8;
    const float* asrc1 = src + (size_t)(rowbase1 + (lane & 15)) * ROWLEN + NUM_DEM + kgrp8;

    f32x4 pacc0[8], pacc1[8];
#pragma unroll
    for (int f = 0; f < 8; ++f) {
        pacc0[f] = (f32x4){0.f, 0.f, 0.f, 0.f};
        pacc1[f] = (f32x4){0.f, 0.f, 0.f, 0.f};
    }
    f32x4 cacc0 = (f32x4){0.f, 0.f, 0.f, 0.f};
    f32x4 cacc1 = cacc0;

    Frag onesf;  // B fragment with col 0 == 1.0 (for row counts), others 0
    {
        unsigned short o = ((lane & 15) == 0) ? (unsigned short)0x3F80 : (unsigned short)0;
        unsigned int ow = (unsigned int)o | ((unsigned int)o << 16);
        onesf.u[0] = ow; onesf.u[1] = ow; onesf.u[2] = ow; onesf.u[3] = ow;
    }

    int t = t0;
    for (; t + 2 <= t1; t += 2) {
        // stage B(t) -> buf0, B(t+1) -> buf1: 2 x 16B per thread (512 threads = 16 KB)
        {
            const unsigned short* gB = bp + (size_t)t * 4096 + tid * 8;
            unsigned short* lB = ldsB + tid * 8;
            GLOAD_LDS16(gB, lB);
            GLOAD_LDS16(gB + 4096, lB + 4096);
        }

        // A for both row-tiles, both steps (perm immediately; regs die early)
        Frag af00, af01, af10, af11;  // af<tile><step>
        LOAD_A_PAIR(asrc0, t, af00, af01);
        LOAD_A_PAIR(asrc1, t, af10, af11);

        __syncthreads();  // both B tiles resident

#pragma unroll
        for (int f = 0; f < 8; ++f) {
            Frag bfr;
            bfr.s = *reinterpret_cast<const s16x8*>(ldsB + f * 512 + lane * 8);
            pacc0[f] = __builtin_amdgcn_mfma_f32_16x16x32_bf16(af00.b, bfr.b, pacc0[f], 0, 0, 0);
            pacc1[f] = __builtin_amdgcn_mfma_f32_16x16x32_bf16(af10.b, bfr.b, pacc1[f], 0, 0, 0);
        }
        cacc0 = __builtin_amdgcn_mfma_f32_16x16x32_bf16(af00.b, onesf.b, cacc0, 0, 0, 0);
        cacc1 = __builtin_amdgcn_mfma_f32_16x16x32_bf16(af10.b, onesf.b, cacc1, 0, 0, 0);
#pragma unroll
        for (int f = 0; f < 8; ++f) {
            Frag bfr;
            bfr.s = *reinterpret_cast<const s16x8*>(ldsB + 4096 + f * 512 + lane * 8);
            pacc0[f] = __builtin_amdgcn_mfma_f32_16x16x32_bf16(af01.b, bfr.b, pacc0[f], 0, 0, 0);
            pacc1[f] = __builtin_amdgcn_mfma_f32_16x16x32_bf16(af11.b, bfr.b, pacc1[f], 0, 0, 0);
        }
        cacc0 = __builtin_amdgcn_mfma_f32_16x16x32_bf16(af01.b, onesf.b, cacc0, 0, 0, 0);
        cacc1 = __builtin_amdgcn_mfma_f32_16x16x32_bf16(af11.b, onesf.b, cacc1, 0, 0, 0);

        __syncthreads();  // protect LDS before next stage
    }
    if (t < t1) {  // odd tail (last chunk)
        {
            const unsigned short* gB = bp + (size_t)t * 4096 + tid * 8;
            GLOAD_LDS16(gB, ldsB + tid * 8);
        }
        Frag af0t, af1t;
        {
            f32x4 z = (f32x4){0.f, 0.f, 0.f, 0.f};
            f32x4 a00 = z, a01 = z, a10 = z, a11 = z;
            if (t * 32 + kgrp8 + 8 <= VOCAB) {
                const f32x4* ap = reinterpret_cast<const f32x4*>(asrc0 + (size_t)t * 32);
                a00 = ap[0];
                a01 = ap[1];
                const f32x4* aq = reinterpret_cast<const f32x4*>(asrc1 + (size_t)t * 32);
                a10 = aq[0];
                a11 = aq[1];
            }
            PERM_A(af0t, a00, a01);
            PERM_A(af1t, a10, a11);
        }
        __syncthreads();
#pragma unroll
        for (int f = 0; f < 8; ++f) {
            Frag bfr;
            bfr.s = *reinterpret_cast<const s16x8*>(ldsB + f * 512 + lane * 8);
            pacc0[f] = __builtin_amdgcn_mfma_f32_16x16x32_bf16(af0t.b, bfr.b, pacc0[f], 0, 0, 0);
            pacc1[f] = __builtin_amdgcn_mfma_f32_16x16x32_bf16(af1t.b, bfr.b, pacc1[f], 0, 0, 0);
        }
        cacc0 = __builtin_amdgcn_mfma_f32_16x16x32_bf16(af0t.b, onesf.b, cacc0, 0, 0, 0);
        cacc1 = __builtin_amdgcn_mfma_f32_16x16x32_bf16(af1t.b, onesf.b, cacc1, 0, 0, 0);
        __syncthreads();
    }

    // epilogue: C/D layout col = lane&15, row = (lane>>4)*4 + reg (both tiles)
    const int rlo = (lane >> 4) * 4;
    float* pch = part + (size_t)ch * NROWS * PCOLS;
#pragma unroll
    for (int f = 0; f < 8; ++f) {
#pragma unroll
        for (int r = 0; r < 4; ++r) {
            pch[(size_t)(rowbase0 + rlo + r) * PCOLS + f * 16 + (lane & 15)] = pacc0[f][r];
            pch[(size_t)(rowbase1 + rlo + r) * PCOLS + f * 16 + (lane & 15)] = pacc1[f][r];
        }
    }
    if ((lane & 15) == 0) {
#pragma unroll
        for (int r = 0; r < 4; ++r) {
            pch[(size_t)(rowbase0 + rlo + r) * PCOLS + 128] = cacc0[r];
            pch[(size_t)(rowbase1 + rlo + r) * PCOLS + 128] = cacc1[r];
        }
    }
}

// ---------------- kernel 2: reduce partials + MLP ----------------------------------
__global__ __launch_bounds__(256) void mlp_k(const float* __restrict__ part,
                                             const float* __restrict__ src,
                                             const float* __restrict__ W1,
                                             const float* __restrict__ b1,
                                             const float* __restrict__ W2,
                                             const float* __restrict__ b2,
                                             float* __restrict__ out, int nch) {
    __shared__ float xls[16][131];  // [dem(2), pooled(128)] per row
    __shared__ float hls[16][16];
    __shared__ float cnt[16];
    const int tid = threadIdx.x;
    const int rb = blockIdx.x * 16;

    if (tid < 16) {
        float s = 0.f;
        for (int c = 0; c < nch; ++c)
            s += part[((size_t)c * NROWS + rb + tid) * PCOLS + 128];
        cnt[tid] = s;
    }
    if (tid >= 16 && tid < 48) {
        int r = (tid - 16) >> 1, d = (tid - 16) & 1;
        xls[r][d] = src[(size_t)(rb + r) * ROWLEN + d];
    }
    __syncthreads();

    for (int idx = tid; idx < 16 * 128; idx += 256) {
        int r = idx >> 7, col = idx & 127;
        float s = 0.f;
        for (int c = 0; c < nch; ++c)
            s += part[((size_t)c * NROWS + rb + r) * PCOLS + col];
        xls[r][NUM_DEM + col] = s / cnt[r];
    }
    __syncthreads();

    {
        int r = tid >> 4, u = tid & 15;
        float acc = b1[u];
        for (int i = 0; i < NUM_DEM + EMB; ++i) acc += xls[r][i] * W1[i * 16 + u];
        hls[r][u] = tanhf(acc);
    }
    __syncthreads();

    if (tid < 32) {
        int r = tid >> 1, o = tid & 1;
        float acc = b2[o];
#pragma unroll
        for (int u = 0; u < 16; ++u) acc += hls[r][u] * W2[u * 2 + o];
        out[(size_t)(rb + r) * 2 + o] = acc;
    }
}

// ---------------- launch ------------------------------------------------------------
extern "C" void kernel_launch(void* const* d_in, const int* in_sizes, int n_in,
                              void* d_out, int out_size, void* d_ws, size_t ws_size,
                              hipStream_t stream) {
    const float* src = (const float*)d_in[0];
    const float* embed = (const float*)d_in[1];
    const float* W1 = (const float*)d_in[2];
    const float* b1 = (const float*)d_in[3];
    const float* W2 = (const float*)d_in[4];
    const float* b2 = (const float*)d_in[5];
    float* out = (float*)d_out;

    unsigned short* bpack = (unsigned short*)d_ws;
    float* part = (float*)((char*)d_ws + BPACK_BYTES);

    const size_t part1 = (size_t)NROWS * PCOLS * sizeof(float);
    int nch = NCH;
    while (nch > 1 && BPACK_BYTES + part1 * (size_t)nch > ws_size) nch >>= 1;

    hipLaunchKernelGGL(pack_embed_k, dim3((KSTEPS * 8 * 64 + 255) / 256), dim3(256), 0,
                       stream, embed, bpack);
    hipLaunchKernelGGL(main_gemm_k, dim3(64 * nch), dim3(512), 0, stream, src, bpack,
                       part, nch);
    hipLaunchKernelGGL(mlp_k, dim3(NROWS / 16), dim3(256), 0, stream, part, src, W1, b1,
                       W2, b2, out, nch);
}

// Round 16
// 184.316 us; speedup vs baseline: 1.2474x; 1.1317x over previous
//
#include <hip/hip_runtime.h>

#define NUM_DEM 2
#define VOCAB 10000
#define EMB 128
#define NROWS 16384
#define ROWLEN (NUM_DEM + VOCAB)      // 10002
#define KSTEPS 313                    // ceil(10000/32)
#define TILES (KSTEPS + 1)            // +1 zero pad tile (pipeline may stage step 313)
#define NITER 157                     // BK=64 iterations total
#define PCOLS 132                     // partial row stride: 128 pooled + 1 count + pad
#define BPACK_USHORTS ((size_t)TILES * 4096)
#define BPACK_BYTES (BPACK_USHORTS * 2)
#define NCH 4

typedef float f32x4 __attribute__((ext_vector_type(4)));
typedef __bf16 bf16x8 __attribute__((ext_vector_type(8)));
typedef short s16x8 __attribute__((ext_vector_type(8)));

union Frag {
    s16x8 s;
    bf16x8 b;
    unsigned int u[4];
};

__device__ __forceinline__ unsigned short f2bf_rtne(float f) {
    unsigned int u = __float_as_uint(f);
    u += 0x7FFFu + ((u >> 16) & 1u);
    return (unsigned short)(u >> 16);
}

// ---------------- kernel 0: pack embed (fp32 -> bf16 MFMA-B fragment order) ---------
// Bpack[((t*8 + c)*64 + l)*8 + j] = bf16(embed[t*32 + (l>>4)*8 + j][c*16 + (l&15)])
// t == 313 is an all-zero pad tile.
__global__ void pack_embed_k(const float* __restrict__ embed,
                             unsigned short* __restrict__ bp) {
    int id = blockIdx.x * blockDim.x + threadIdx.x;
    if (id >= TILES * 8 * 64) return;
    int l = id & 63;
    int c = (id >> 6) & 7;
    int t = id >> 9;
    int kbase = t * 32 + ((l >> 4) * 8);
    int n = c * 16 + (l & 15);
    unsigned short v[8];
#pragma unroll
    for (int j = 0; j < 8; ++j) {
        int k = kbase + j;
        float f = (k < VOCAB) ? embed[(size_t)k * EMB + n] : 0.0f;
        v[j] = f2bf_rtne(f);
    }
    uint4 w;
    w.x = (unsigned int)v[0] | ((unsigned int)v[1] << 16);
    w.y = (unsigned int)v[2] | ((unsigned int)v[3] << 16);
    w.z = (unsigned int)v[4] | ((unsigned int)v[5] << 16);
    w.w = (unsigned int)v[6] | ((unsigned int)v[7] << 16);
    *reinterpret_cast<uint4*>(bp + (size_t)id * 8) = w;
}

// ---------------- kernel 1: split-K masked-sum GEMM, M=128 + counted-vmcnt ----------
// R13 geometry (512 threads, 8 waves, M=128, BK=64, nch=4, 2 blocks/CU) with R10's
// counted-vmcnt double-buffered pipeline: per iter, steady-state wait is
// s_waitcnt vmcnt(6) (iter i+1's 2 B-gloads + 4 A-loads stay in flight), bare
// s_barriers, no vmcnt(0) drain in the loop.
typedef const __attribute__((address_space(1))) unsigned int* gas_u32p;
typedef __attribute__((address_space(3))) unsigned int* las_u32p;
#define GLOAD_LDS16(g, l)                                                              \
    __builtin_amdgcn_global_load_lds((gas_u32p)(g), (las_u32p)(l), 16, 0, 0)

#define PERM_A(dst, x0, x1)                                                            \
    dst.u[0] = __builtin_amdgcn_perm(__float_as_uint(x0.y), __float_as_uint(x0.x),     \
                                     0x07060302u);                                     \
    dst.u[1] = __builtin_amdgcn_perm(__float_as_uint(x0.w), __float_as_uint(x0.z),     \
                                     0x07060302u);                                     \
    dst.u[2] = __builtin_amdgcn_perm(__float_as_uint(x1.y), __float_as_uint(x1.x),     \
                                     0x07060302u);                                     \
    dst.u[3] = __builtin_amdgcn_perm(__float_as_uint(x1.w), __float_as_uint(x1.z),     \
                                     0x07060302u);

#define WAITVM(N) asm volatile("s_waitcnt vmcnt(" #N ")" ::: "memory")

// stage iter G's two 32-k tiles into LDS buffer BUF: 2 x 16B per thread (512 thr)
#define STAGE_B(G, BUF)                                                                \
    {                                                                                  \
        const unsigned short* gB_ = bp + (size_t)(2 * (G)) * 4096 + tid * 8;           \
        unsigned short* lB_ = &ldsB[BUF][0] + tid * 8;                                 \
        GLOAD_LDS16(gB_, lB_);                                                         \
        GLOAD_LDS16(gB_ + 4096, lB_ + 4096);                                           \
    }

// unconditional clamped A loads for iter G (4 vmem): OOB groups zeroed at consume
#define LOAD_A2(G, A0, A1, A2, A3)                                                     \
    {                                                                                  \
        const int s0_ = 2 * (G), s1_ = s0_ + 1;                                        \
        const f32x4* p0_ = reinterpret_cast<const f32x4*>(                             \
            asrc + ((s0_ * 32 + kgrp8 + 8 <= VOCAB) ? (size_t)(s0_ * 32) : (size_t)0));\
        const f32x4* p1_ = reinterpret_cast<const f32x4*>(                             \
            asrc + ((s1_ * 32 + kgrp8 + 8 <= VOCAB) ? (size_t)(s1_ * 32) : (size_t)0));\
        A0 = p0_[0];                                                                   \
        A1 = p0_[1];                                                                   \
        A2 = p1_[0];                                                                   \
        A3 = p1_[1];                                                                   \
    }

#define BODY(G, BUF, A0, A1, A2, A3, DOPF, PFG, N)                                     \
    {                                                                                  \
        WAITVM(N);                                                                     \
        __builtin_amdgcn_s_barrier();                                                  \
        asm volatile("" ::: "memory"); /* pin ds_reads below the barrier */            \
        {                                                                              \
            const int s0_ = 2 * (G), s1_ = s0_ + 1;                                    \
            Frag af0_, af1_;                                                           \
            PERM_A(af0_, A0, A1); /* fp32 0/1 -> bf16 truncation exact */              \
            PERM_A(af1_, A2, A3);                                                      \
            unsigned v0_ = (s0_ * 32 + kgrp8 + 8 <= VOCAB) ? 0xFFFFFFFFu : 0u;         \
            unsigned v1_ = (s1_ * 32 + kgrp8 + 8 <= VOCAB) ? 0xFFFFFFFFu : 0u;         \
            af0_.u[0] &= v0_; af0_.u[1] &= v0_; af0_.u[2] &= v0_; af0_.u[3] &= v0_;    \
            af1_.u[0] &= v1_; af1_.u[1] &= v1_; af1_.u[2] &= v1_; af1_.u[3] &= v1_;    \
            const unsigned short* rB_ = &ldsB[BUF][0] + lane * 8;                      \
            _Pragma("unroll") for (int f = 0; f < 8; ++f) {                            \
                Frag bfr_;                                                             \
                bfr_.s = *reinterpret_cast<const s16x8*>(rB_ + f * 512);               \
                pacc[f] = __builtin_amdgcn_mfma_f32_16x16x32_bf16(af0_.b, bfr_.b,      \
                                                                  pacc[f], 0, 0, 0);   \
            }                                                                          \
            cacc = __builtin_amdgcn_mfma_f32_16x16x32_bf16(af0_.b, onesf.b, cacc, 0,   \
                                                           0, 0);                      \
            _Pragma("unroll") for (int f = 0; f < 8; ++f) {                            \
                Frag bfr_;                                                             \
                bfr_.s = *reinterpret_cast<const s16x8*>(rB_ + 4096 + f * 512);        \
                pacc[f] = __builtin_amdgcn_mfma_f32_16x16x32_bf16(af1_.b, bfr_.b,      \
                                                                  pacc[f], 0, 0, 0);   \
            }                                                                          \
            cacc = __builtin_amdgcn_mfma_f32_16x16x32_bf16(af1_.b, onesf.b, cacc, 0,   \
                                                           0, 0);                      \
        }                                                                              \
        asm volatile("" ::: "memory"); /* pin ds_reads above this barrier */           \
        __builtin_amdgcn_s_barrier();                                                  \
        __builtin_amdgcn_sched_barrier(0);                                             \
        if (DOPF) {                                                                    \
            STAGE_B(PFG, BUF);                                                         \
            LOAD_A2(PFG, A0, A1, A2, A3);                                              \
        }                                                                              \
    }

__global__ __launch_bounds__(512, 4) void main_gemm_k(
    const float* __restrict__ src, const unsigned short* __restrict__ bp,
    float* __restrict__ part, int nch) {
    __shared__ alignas(16) unsigned short ldsB[2][2 * 4096];  // 32 KB double buffer

    const int tid = threadIdx.x;
    const int lane = tid & 63;
    const int wid = tid >> 6;        // 0..7
    const int rb = blockIdx.x & 127; // row block: 128 rows
    const int ch = blockIdx.x >> 7;  // K chunk (iter-granular)
    const int I0 = (NITER * ch) / NCH;
    const int I1 = (NITER * (ch + 1)) / NCH;
    const int nIter = I1 - I0;  // 39 or 40

    const int rowbase = rb * 128 + wid * 16;
    const int arow = rowbase + (lane & 15);
    const int kgrp8 = (lane >> 4) * 8;
    const float* asrc = src + (size_t)arow * ROWLEN + NUM_DEM + kgrp8;

    f32x4 pacc[8];
#pragma unroll
    for (int f = 0; f < 8; ++f) pacc[f] = (f32x4){0.f, 0.f, 0.f, 0.f};
    f32x4 cacc = (f32x4){0.f, 0.f, 0.f, 0.f};

    Frag onesf;  // B fragment with col 0 == 1.0 (row counts), others 0
    {
        unsigned short o = ((lane & 15) == 0) ? (unsigned short)0x3F80 : (unsigned short)0;
        unsigned int ow = (unsigned int)o | ((unsigned int)o << 16);
        onesf.u[0] = ow; onesf.u[1] = ow; onesf.u[2] = ow; onesf.u[3] = ow;
    }

    f32x4 aP0, aP1, aP2, aP3, aQ0, aQ1, aQ2, aQ3;  // A slots, parity-named (rule #20)

    // prologue: iters I0 -> buf0/P, I0+1 -> buf1/Q (groups fenced for vmcnt order)
    STAGE_B(I0, 0);
    LOAD_A2(I0, aP0, aP1, aP2, aP3);
    asm volatile("" ::: "memory");
    STAGE_B(I0 + 1, 1);
    LOAD_A2(I0 + 1, aQ0, aQ1, aQ2, aQ3);
    // outstanding: B(0)+A(0) = 6, B(1)+A(1) = 6 -> steady-state wait = vmcnt(6)

    int i = 0;
    for (; i + 3 < nIter; i += 2) {
        BODY(I0 + i, 0, aP0, aP1, aP2, aP3, 1, I0 + i + 2, 6);
        BODY(I0 + i + 1, 1, aQ0, aQ1, aQ2, aQ3, 1, I0 + i + 3, 6);
    }
    if (nIter - i == 3) {
        BODY(I0 + i, 0, aP0, aP1, aP2, aP3, 1, I0 + i + 2, 6);
        BODY(I0 + i + 1, 1, aQ0, aQ1, aQ2, aQ3, 0, 0, 6);
        BODY(I0 + i + 2, 0, aP0, aP1, aP2, aP3, 0, 0, 0);
    } else {  // nIter - i == 2
        BODY(I0 + i, 0, aP0, aP1, aP2, aP3, 0, 0, 6);
        BODY(I0 + i + 1, 1, aQ0, aQ1, aQ2, aQ3, 0, 0, 0);
    }

    // epilogue: C/D layout col = lane&15, row = (lane>>4)*4 + reg
    const int rlo = (lane >> 4) * 4;
    float* pch = part + (size_t)ch * NROWS * PCOLS;
#pragma unroll
    for (int f = 0; f < 8; ++f) {
#pragma unroll
        for (int r = 0; r < 4; ++r) {
            int row = rowbase + rlo + r;
            pch[(size_t)row * PCOLS + f * 16 + (lane & 15)] = pacc[f][r];
        }
    }
    if ((lane & 15) == 0) {
#pragma unroll
        for (int r = 0; r < 4; ++r) {
            int row = rowbase + rlo + r;
            pch[(size_t)row * PCOLS + 128] = cacc[r];
        }
    }
}

// ---------------- kernel 2: reduce partials + MLP ----------------------------------
__global__ __launch_bounds__(256) void mlp_k(const float* __restrict__ part,
                                             const float* __restrict__ src,
                                             const float* __restrict__ W1,
                                             const float* __restrict__ b1,
                                             const float* __restrict__ W2,
                                             const float* __restrict__ b2,
                                             float* __restrict__ out, int nch) {
    __shared__ float xls[16][131];  // [dem(2), pooled(128)] per row
    __shared__ float hls[16][16];
    __shared__ float cnt[16];
    const int tid = threadIdx.x;
    const int rb = blockIdx.x * 16;

    if (tid < 16) {
        float s = 0.f;
        for (int c = 0; c < nch; ++c)
            s += part[((size_t)c * NROWS + rb + tid) * PCOLS + 128];
        cnt[tid] = s;
    }
    if (tid >= 16 && tid < 48) {
        int r = (tid - 16) >> 1, d = (tid - 16) & 1;
        xls[r][d] = src[(size_t)(rb + r) * ROWLEN + d];
    }
    __syncthreads();

    for (int idx = tid; idx < 16 * 128; idx += 256) {
        int r = idx >> 7, col = idx & 127;
        float s = 0.f;
        for (int c = 0; c < nch; ++c)
            s += part[((size_t)c * NROWS + rb + r) * PCOLS + col];
        xls[r][NUM_DEM + col] = s / cnt[r];
    }
    __syncthreads();

    {
        int r = tid >> 4, u = tid & 15;
        float acc = b1[u];
        for (int i = 0; i < NUM_DEM + EMB; ++i) acc += xls[r][i] * W1[i * 16 + u];
        hls[r][u] = tanhf(acc);
    }
    __syncthreads();

    if (tid < 32) {
        int r = tid >> 1, o = tid & 1;
        float acc = b2[o];
#pragma unroll
        for (int u = 0; u < 16; ++u) acc += hls[r][u] * W2[u * 2 + o];
        out[(size_t)(rb + r) * 2 + o] = acc;
    }
}

// ---------------- launch ------------------------------------------------------------
extern "C" void kernel_launch(void* const* d_in, const int* in_sizes, int n_in,
                              void* d_out, int out_size, void* d_ws, size_t ws_size,
                              hipStream_t stream) {
    const float* src = (const float*)d_in[0];
    const float* embed = (const float*)d_in[1];
    const float* W1 = (const float*)d_in[2];
    const float* b1 = (const float*)d_in[3];
    const float* W2 = (const float*)d_in[4];
    const float* b2 = (const float*)d_in[5];
    float* out = (float*)d_out;

    unsigned short* bpack = (unsigned short*)d_ws;
    float* part = (float*)((char*)d_ws + BPACK_BYTES);

    hipLaunchKernelGGL(pack_embed_k, dim3((TILES * 8 * 64 + 255) / 256), dim3(256), 0,
                       stream, embed, bpack);
    hipLaunchKernelGGL(main_gemm_k, dim3(128 * NCH), dim3(512), 0, stream, src, bpack,
                       part, NCH);
    hipLaunchKernelGGL(mlp_k, dim3(NROWS / 16), dim3(256), 0, stream, part, src, W1, b1,
                       W2, b2, out, NCH);
}